// Round 16
// baseline (116.333 us; speedup 1.0000x reference)
//
#include <hip/hip_runtime.h>

#define BATCH 65536
#define NT 256
#define NTG 512
#define MFMA __builtin_amdgcn_mfma_f32_16x16x32_bf16

typedef short bf16x8 __attribute__((ext_vector_type(8)));
typedef float f32x4 __attribute__((ext_vector_type(4)));
typedef unsigned short u16x8 __attribute__((ext_vector_type(8)));
typedef unsigned short u16x4 __attribute__((ext_vector_type(4)));

__device__ __forceinline__ float sigmoidf_(float x) { return 1.0f / (1.0f + __expf(-x)); }
__device__ __forceinline__ float tanhf_(float x) { return 2.0f / (1.0f + __expf(-2.0f * x)) - 1.0f; }
__device__ __forceinline__ unsigned short f2b(float f) {
  union { float f; unsigned int u; } v; v.f = f;
  unsigned int r = (v.u + 0x7FFFu + ((v.u >> 16) & 1u)) >> 16;
  return (unsigned short)r;
}
__device__ __forceinline__ float b2f(unsigned short u) {
  return __uint_as_float(((unsigned int)u) << 16);
}
__device__ __forceinline__ bf16x8 cvt8(float4 a, float4 b) {
  union { unsigned short u[8]; bf16x8 v; } t;
  t.u[0] = f2b(a.x); t.u[1] = f2b(a.y); t.u[2] = f2b(a.z); t.u[3] = f2b(a.w);
  t.u[4] = f2b(b.x); t.u[5] = f2b(b.y); t.u[6] = f2b(b.z); t.u[7] = f2b(b.w);
  return t.v;
}

// ---------------- prep (standalone launch; ordering vs k_all via stream) ----------------
// wsW per cell: 24576 u16 FRAGMENT ORDER: frag (jt,q) at ((jt*12+q)*64+lane)*8+e.
__global__ __launch_bounds__(NT) void k_prep(
    const float* __restrict__ W0, const float* __restrict__ W1,
    const float* __restrict__ W2, const float* __restrict__ W3,
    const float* __restrict__ W4, const float* __restrict__ W5,
    const float* __restrict__ W6, const float* __restrict__ W7,
    const float* __restrict__ bi0, const float* __restrict__ bi1,
    const float* __restrict__ bi2, const float* __restrict__ bi3,
    const float* __restrict__ bh0, const float* __restrict__ bh1,
    const float* __restrict__ bh2, const float* __restrict__ bh3,
    const float* __restrict__ aw1, const float* __restrict__ cw1,
    const float* __restrict__ w3s,
    unsigned short* __restrict__ wsW, unsigned short* __restrict__ wsH,
    unsigned short* __restrict__ wsW3, float* __restrict__ wsB) {
  const int y = blockIdx.y;
  const int i = blockIdx.x * NT + threadIdx.x;
  if (y < 8) {
    if (i >= 12288) return;
    const float* src = (y == 0) ? W0 : (y == 1) ? W1 : (y == 2) ? W2 : (y == 3) ? W3
                     : (y == 4) ? W4 : (y == 5) ? W5 : (y == 6) ? W6 : W7;
    const int c = y >> 1, p = y & 1;
    const int j = i >> 6, k = i & 63;
    const int g = j >> 6, jrow = j & 63;
    const int jt = jrow >> 4, r16i = jrow & 15;
    const int kseg = k >> 5, kgv = (k & 31) >> 3, e = k & 7;
    const int lane = kgv * 16 + r16i;
    const int q = g * 4 + p * 2 + kseg;
    wsW[c * 24576 + ((jt * 12 + q) * 64 + lane) * 8 + e] = f2b(src[i]);
  } else if (y == 8) {
    if (i < 4096) wsH[i] = f2b(aw1[i]);
  } else if (y == 9) {
    if (i < 4096) wsH[4096 + i] = f2b(cw1[i]);
  } else if (y == 10) {
    if (i < 8192) wsW3[i] = f2b(w3s[i]);
  } else {
    const int c = y - 11;
    if (i < 256) {
      const float* bi = (c == 0) ? bi0 : (c == 1) ? bi1 : (c == 2) ? bi2 : bi3;
      const float* bh = (c == 0) ? bh0 : (c == 1) ? bh1 : (c == 2) ? bh2 : bh3;
      const int j = i & 63, g = i >> 6;
      float v = (g == 0) ? bi[j] + bh[j]
              : (g == 1) ? bi[64 + j] + bh[64 + j]
              : (g == 2) ? bi[128 + j] : bh[128 + j];
      wsB[c * 256 + i] = v;
    }
  }
}

// ---------------- k_all: conv1+conv2 (LDS) -> conv3-GEMM -> 4 GRU cells -> heads ----
// 512 thr / 128 samples. LDS time-multiplex (75.5KB peak, 2 blocks/CU):
//   conv:  obs_b[128*149] @0 (38.1KB) | pooled[128*146] @19072 u16 (37.4KB)
//   c2:    c2l[128*136]  @0 (34.8KB)  (obs dead)
//   gru:   wlds[24576]   @0 (48KB)    (c2 dead) | xls[128*88] @24576 u16 (22.5KB)
#define OSTR 149
#define PSTR 146
#define CSTR 136
#define XSTR 88
__global__ __launch_bounds__(NTG, 4) void k_all(
    const float* __restrict__ obs, const float* __restrict__ w1,
    const float* __restrict__ b1, const float* __restrict__ w2,
    const float* __restrict__ b2,
    const float* __restrict__ memF,
    const unsigned short* __restrict__ wsW,
    const unsigned short* __restrict__ wsW3,
    const float* __restrict__ wsB,
    const unsigned short* __restrict__ wsH,
    const float* __restrict__ b3,
    const float* __restrict__ ab1, const float* __restrict__ cb1,
    const float* __restrict__ aw2, const float* __restrict__ ab2,
    const float* __restrict__ cw2, const float* __restrict__ cb2,
    float* __restrict__ out) {
  __shared__ __align__(16) unsigned short smem[37760];   // 75520 B
  unsigned short* obs_b = smem;                 // conv phase
  unsigned short* pooled = smem + 19072;        // conv phase
  unsigned short* c2l = smem;                   // after conv1 (obs dead)
  unsigned short* wlds = smem;                  // after stage0 (c2 dead)
  unsigned short* xls = smem + 24576;           // gru phase (pooled dead)
  const int tid = threadIdx.x;
  const int lane = tid & 63;
  const int wave = tid >> 6;            // 0..7
  const int r16 = lane & 15;
  const int kg = lane >> 4;
  const int wbase = wave * 16;
  const int blk_base = blockIdx.x * 128;
  const int m_base = blk_base + wbase;
  float* outMem = out + (size_t)4 * BATCH;

  // ---- phase A: stage 128 samples' obs (coalesced float4 -> bf16 LDS) ----
  {
    const float4* src = (const float4*)(obs + (size_t)blk_base * 147);
#pragma unroll 1
    for (int i = tid; i < 4704; i += NTG) {
      const float4 v = src[i];
      int idx = i * 4;
      int s = idx / 147;
      int c = idx - s * 147;
      obs_b[s * OSTR + c] = f2b(v.x);
      if (++c == 147) { c = 0; ++s; } obs_b[s * OSTR + c] = f2b(v.y);
      if (++c == 147) { c = 0; ++s; } obs_b[s * OSTR + c] = f2b(v.z);
      if (++c == 147) { c = 0; ++s; } obs_b[s * OSTR + c] = f2b(v.w);
    }
  }
  __syncthreads();

  // ---- phase B: conv1 (2x2,3->16) + ReLU + maxpool2 -> pooled ----
  {
    const int s = tid & 127;
    const int ph = tid >> 7;           // 0..3; ph<3 active
    if (ph < 3) {
      float r[3][21];
#pragma unroll
      for (int rr = 0; rr < 3; ++rr)
#pragma unroll
        for (int i = 0; i < 21; ++i) r[rr][i] = b2f(obs_b[s * OSTR + (2 * ph + rr) * 21 + i]);
#pragma unroll 1
      for (int oc = 0; oc < 16; ++oc) {
        float wv[12];
#pragma unroll
        for (int i = 0; i < 12; ++i) wv[i] = w1[oc * 12 + i];
        const float bias = b1[oc];
#pragma unroll
        for (int pw = 0; pw < 3; ++pw) {
          float m = 0.0f;
#pragma unroll
          for (int dh = 0; dh < 2; ++dh)
#pragma unroll
            for (int dw = 0; dw < 2; ++dw) {
              float acc = bias;
#pragma unroll
              for (int kh = 0; kh < 2; ++kh)
#pragma unroll
                for (int kw = 0; kw < 2; ++kw)
#pragma unroll
                  for (int c = 0; c < 3; ++c)
                    acc += r[dh + kh][(2 * pw + dw + kw) * 3 + c] * wv[c * 4 + kh * 2 + kw];
              m = fmaxf(m, fmaxf(acc, 0.0f));
            }
          pooled[s * PSTR + oc * 9 + ph * 3 + pw] = f2b(m);
        }
      }
    }
  }
  __syncthreads();

  // ---- phase C: conv2 (2x2,16->32) + ReLU -> c2l (overwrites obs region) ----
  {
    const int s = tid & 127;
    const int g = tid >> 7;            // 0..3, 8 oc each
    const int ocb = g * 8;
    float acc[8][4];
#pragma unroll
    for (int u = 0; u < 8; ++u) {
      const float bb = b2[ocb + u];
      acc[u][0] = bb; acc[u][1] = bb; acc[u][2] = bb; acc[u][3] = bb;
    }
#pragma unroll 1
    for (int ic = 0; ic < 16; ++ic) {
      float p9[9];
#pragma unroll
      for (int p = 0; p < 9; ++p) p9[p] = b2f(pooled[s * PSTR + ic * 9 + p]);
#pragma unroll
      for (int u = 0; u < 8; ++u) {
        float w[4];
#pragma unroll
        for (int i = 0; i < 4; ++i) w[i] = w2[((ocb + u) * 16 + ic) * 4 + i];
#pragma unroll
        for (int oh = 0; oh < 2; ++oh)
#pragma unroll
          for (int ow = 0; ow < 2; ++ow)
            acc[u][oh * 2 + ow] += p9[(oh + 0) * 3 + (ow + 0)] * w[0] +
                                   p9[(oh + 0) * 3 + (ow + 1)] * w[1] +
                                   p9[(oh + 1) * 3 + (ow + 0)] * w[2] +
                                   p9[(oh + 1) * 3 + (ow + 1)] * w[3];
      }
    }
    unsigned short ob[32];
#pragma unroll
    for (int u = 0; u < 8; ++u)
#pragma unroll
      for (int p = 0; p < 4; ++p) ob[u * 4 + p] = f2b(fmaxf(acc[u][p], 0.0f));
    __syncthreads();   // pooled reads done block-wide before c2l overwrites obs
#pragma unroll
    for (int i = 0; i < 4; ++i)
      *(u16x8*)(c2l + s * CSTR + g * 32 + 8 * i) = *(const u16x8*)(ob + 8 * i);
  }
  __syncthreads();

  // ---- phase D: stage0 conv3-GEMM (A from c2l), + cell-0 weight loads ----
  float4 wst[6];
  {
    const float4* wsrc = (const float4*)wsW;
#pragma unroll
    for (int r = 0; r < 6; ++r) wst[r] = wsrc[r * NTG + tid];
  }
  float4 hraw[4];
  {
    const float* hp = memF + (size_t)(m_base + r16) * 256 + kg * 8;
    hraw[0] = *(const float4*)(hp);
    hraw[1] = *(const float4*)(hp + 4);
    hraw[2] = *(const float4*)(hp + 32);
    hraw[3] = *(const float4*)(hp + 36);
  }
  {
    bf16x8 a0[4];
    const unsigned short* ap = c2l + (wbase + r16) * CSTR + kg * 8;
#pragma unroll
    for (int f = 0; f < 4; ++f) a0[f] = *(const bf16x8*)(ap + f * 32);
#pragma unroll
    for (int n = 0; n < 4; ++n) {
      const unsigned short* bp = wsW3 + (size_t)(n * 16 + r16) * 128 + kg * 8;
      f32x4 q0 = (f32x4)(0.0f);
#pragma unroll
      for (int f = 0; f < 4; ++f) {
        bf16x8 bb = *(const bf16x8*)(bp + f * 32);
        q0 = MFMA(bb, a0[f], q0, 0, 0, 0);
      }
      const f32x4 b4 = *(const f32x4*)(b3 + n * 16 + kg * 4);
      u16x4 xo;
#pragma unroll
      for (int q = 0; q < 4; ++q) xo[q] = f2b(fmaxf(q0[q] + b4[q], 0.0f));
      // xls region overlaps old pooled only; c2l reads above are complete per-wave,
      // but other waves may still read c2l -> xls is disjoint from c2l, safe.
      *(u16x4*)(xls + (wbase + r16) * XSTR + n * 16 + kg * 4) = xo;
    }
  }
  __syncthreads();
  // publish cell-0 weights (overwrites c2l)
  {
    float4* wd = (float4*)wlds;
#pragma unroll
    for (int r = 0; r < 6; ++r) wd[r * NTG + tid] = wst[r];
  }
  __syncthreads();

  // ---- 4 GRU cells (R13 structure, unchanged) ----
#pragma unroll 1
  for (int c = 0; c < 4; ++c) {
    const int co = c * 64;
    const float* bcp = wsB + c * 256;
    bf16x8 ax0, ax1, ah0, ah1;
    {
      const unsigned short* xp = xls + (wbase + r16) * XSTR + kg * 8;
      ax0 = *(const bf16x8*)(xp);
      ax1 = *(const bf16x8*)(xp + 32);
    }
    ah0 = cvt8(make_float4(hraw[0].x, hraw[0].y, hraw[0].z, hraw[0].w),
               make_float4(hraw[1].x, hraw[1].y, hraw[1].z, hraw[1].w));
    ah1 = cvt8(make_float4(hraw[2].x, hraw[2].y, hraw[2].z, hraw[2].w),
               make_float4(hraw[3].x, hraw[3].y, hraw[3].z, hraw[3].w));
    if (c < 3) {
      const float* hp = memF + (size_t)(m_base + r16) * 256 + (c + 1) * 64 + kg * 8;
      hraw[0] = *(const float4*)(hp);
      hraw[1] = *(const float4*)(hp + 4);
      hraw[2] = *(const float4*)(hp + 32);
      hraw[3] = *(const float4*)(hp + 36);
    }
    const unsigned short* wl = wlds + lane * 8;
#pragma unroll 1
    for (int jt = 0; jt < 4; ++jt) {
      const unsigned short* wjt = wl + jt * 6144;
      bf16x8 xr0 = *(const bf16x8*)(wjt);
      bf16x8 xr1 = *(const bf16x8*)(wjt + 512);
      bf16x8 hr0 = *(const bf16x8*)(wjt + 1024);
      bf16x8 hr1 = *(const bf16x8*)(wjt + 1536);
      bf16x8 xz0 = *(const bf16x8*)(wjt + 2048);
      bf16x8 xz1 = *(const bf16x8*)(wjt + 2560);
      bf16x8 hz0 = *(const bf16x8*)(wjt + 3072);
      bf16x8 hz1 = *(const bf16x8*)(wjt + 3584);
      bf16x8 xn0 = *(const bf16x8*)(wjt + 4096);
      bf16x8 xn1 = *(const bf16x8*)(wjt + 4608);
      bf16x8 hn0 = *(const bf16x8*)(wjt + 5120);
      bf16x8 hn1 = *(const bf16x8*)(wjt + 5632);
      f32x4 sr = (f32x4)(0.0f), sz = (f32x4)(0.0f), sn = (f32x4)(0.0f), tn = (f32x4)(0.0f);
      sr = MFMA(xr0, ax0, sr, 0, 0, 0);
      sr = MFMA(xr1, ax1, sr, 0, 0, 0);
      sr = MFMA(hr0, ah0, sr, 0, 0, 0);
      sr = MFMA(hr1, ah1, sr, 0, 0, 0);
      sz = MFMA(xz0, ax0, sz, 0, 0, 0);
      sz = MFMA(xz1, ax1, sz, 0, 0, 0);
      sz = MFMA(hz0, ah0, sz, 0, 0, 0);
      sz = MFMA(hz1, ah1, sz, 0, 0, 0);
      sn = MFMA(xn0, ax0, sn, 0, 0, 0);
      sn = MFMA(xn1, ax1, sn, 0, 0, 0);
      tn = MFMA(hn0, ah0, tn, 0, 0, 0);
      tn = MFMA(hn1, ah1, tn, 0, 0, 0);
      const int jb = jt * 16 + kg * 4;
      const f32x4 ho4 = *(const f32x4*)(memF + (size_t)(m_base + r16) * 256 + co + jb);
      const f32x4 rb4 = *(const f32x4*)(bcp + jb);
      const f32x4 zb4 = *(const f32x4*)(bcp + 64 + jb);
      const f32x4 ib4 = *(const f32x4*)(bcp + 128 + jb);
      const f32x4 hb4 = *(const f32x4*)(bcp + 192 + jb);
      f32x4 nhv;
      u16x4 xo;
#pragma unroll
      for (int q = 0; q < 4; ++q) {
        const float rg = sigmoidf_(sr[q] + rb4[q]);
        const float zg = sigmoidf_(sz[q] + zb4[q]);
        const float ng = tanhf_((sn[q] + ib4[q]) + rg * (tn[q] + hb4[q]));
        const float nh = (1.0f - zg) * ng + zg * ho4[q];
        nhv[q] = nh;
        xo[q] = f2b(nh);
      }
      *(f32x4*)(outMem + (size_t)(m_base + r16) * 256 + co + jb) = nhv;
      *(u16x4*)(xls + (wbase + r16) * XSTR + jb) = xo;
    }
    if (c < 3) {
      __syncthreads();
      const float4* wsrc = (const float4*)(wsW + (size_t)(c + 1) * 24576);
      float4* wd = (float4*)wlds;
#pragma unroll
      for (int r = 0; r < 6; ++r) wd[r * NTG + tid] = wsrc[r * NTG + tid];
      __syncthreads();
    }
  }

  // ---- heads ----
  bf16x8 ex0, ex1;
  {
    const unsigned short* xp = xls + (wbase + r16) * XSTR + kg * 8;
    ex0 = *(const bf16x8*)(xp);
    ex1 = *(const bf16x8*)(xp + 32);
  }
  f32x4 ha[8];
#pragma unroll
  for (int n = 0; n < 8; ++n) ha[n] = (f32x4)(0.0f);
#pragma unroll
  for (int n = 0; n < 8; ++n) {
    const unsigned short* wp = wsH + (size_t)(n * 16 + r16) * 64 + kg * 8;
    bf16x8 b0 = *(const bf16x8*)(wp);
    bf16x8 b1 = *(const bf16x8*)(wp + 32);
    ha[n] = MFMA(b0, ex0, ha[n], 0, 0, 0);
    ha[n] = MFMA(b1, ex1, ha[n], 0, 0, 0);
  }
  float l0 = 0.0f, l1 = 0.0f, l2 = 0.0f, vv = 0.0f;
  const int jb0 = kg * 4;
#pragma unroll
  for (int t = 0; t < 4; ++t) {
    const f32x4 ba4 = *(const f32x4*)(ab1 + t * 16 + jb0);
    const f32x4 w0 = *(const f32x4*)(aw2 + t * 16 + jb0);
    const f32x4 w1v = *(const f32x4*)(aw2 + 64 + t * 16 + jb0);
    const f32x4 w2v = *(const f32x4*)(aw2 + 128 + t * 16 + jb0);
    const f32x4 bc4 = *(const f32x4*)(cb1 + t * 16 + jb0);
    const f32x4 wc4 = *(const f32x4*)(cw2 + t * 16 + jb0);
#pragma unroll
    for (int q = 0; q < 4; ++q) {
      const float av = fmaxf(ha[t][q] + ba4[q], 0.0f);
      const float cv = fmaxf(ha[t + 4][q] + bc4[q], 0.0f);
      l0 += av * w0[q]; l1 += av * w1v[q]; l2 += av * w2v[q];
      vv += cv * wc4[q];
    }
  }
  l0 += __shfl_xor(l0, 16); l0 += __shfl_xor(l0, 32);
  l1 += __shfl_xor(l1, 16); l1 += __shfl_xor(l1, 32);
  l2 += __shfl_xor(l2, 16); l2 += __shfl_xor(l2, 32);
  vv += __shfl_xor(vv, 16); vv += __shfl_xor(vv, 32);
  if (kg == 0) {
    const int sq = m_base + r16;
    const float g0 = l0 + ab2[0], g1 = l1 + ab2[1], g2 = l2 + ab2[2];
    const float mx = fmaxf(g0, fmaxf(g1, g2));
    const float lse = mx + __logf(__expf(g0 - mx) + __expf(g1 - mx) + __expf(g2 - mx));
    out[(size_t)sq * 3 + 0] = g0 - lse;
    out[(size_t)sq * 3 + 1] = g1 - lse;
    out[(size_t)sq * 3 + 2] = g2 - lse;
    out[(size_t)3 * BATCH + sq] = vv + cb2[0];
  }
}

extern "C" void kernel_launch(void* const* d_in, const int* in_sizes, int n_in,
                              void* d_out, int out_size, void* d_ws, size_t ws_size,
                              hipStream_t stream) {
  (void)in_sizes; (void)n_in; (void)out_size; (void)ws_size;
  const float* obs = (const float*)d_in[0];
  const float* mem = (const float*)d_in[1];
  const float* w1 = (const float*)d_in[2];
  const float* b1 = (const float*)d_in[3];
  const float* w2 = (const float*)d_in[4];
  const float* b2 = (const float*)d_in[5];
  const float* w3 = (const float*)d_in[6];
  const float* b3 = (const float*)d_in[7];
  const float* gw[16];
  for (int i = 0; i < 16; ++i) gw[i] = (const float*)d_in[8 + i];
  const float* aw1 = (const float*)d_in[24];
  const float* ab1 = (const float*)d_in[25];
  const float* aw2 = (const float*)d_in[26];
  const float* ab2 = (const float*)d_in[27];
  const float* cw1 = (const float*)d_in[28];
  const float* cb1 = (const float*)d_in[29];
  const float* cw2 = (const float*)d_in[30];
  const float* cb2 = (const float*)d_in[31];

  float* out = (float*)d_out;

  unsigned short* wsW = (unsigned short*)d_ws;                 // 4*24576
  unsigned short* wsH = wsW + 98304;                           // 8192
  unsigned short* wsW3 = wsH + 8192;                           // 8192
  float* wsB = (float*)(wsW3 + 8192);                          // 1024 f32

  hipLaunchKernelGGL(k_prep, dim3(48, 15), dim3(NT), 0, stream,
                     gw[0], gw[1], gw[4], gw[5], gw[8], gw[9], gw[12], gw[13],
                     gw[2], gw[6], gw[10], gw[14],
                     gw[3], gw[7], gw[11], gw[15],
                     aw1, cw1, w3, wsW, wsH, wsW3, wsB);
  hipLaunchKernelGGL(k_all, dim3(BATCH / 128), dim3(NTG), 0, stream,
                     obs, w1, b1, w2, b2, mem, wsW, wsW3, wsB, wsH, b3,
                     ab1, cb1, aw2, ab2, cw2, cb2, out);
}